// Round 17
// baseline (184.515 us; speedup 1.0000x reference)
//
#include <hip/hip_runtime.h>
#include <math.h>

#define HW 9216
#define WD 96
#define NC 128

typedef unsigned short u16;
typedef __attribute__((ext_vector_type(8))) short short8;
typedef __attribute__((ext_vector_type(4))) float v4f;

__device__ __forceinline__ int rfl(int v){ return __builtin_amdgcn_readfirstlane(v); }
__device__ __forceinline__ float bu2f(u16 s){ return __uint_as_float(((unsigned)s)<<16); }
__device__ __forceinline__ u16 f2b(float f){ unsigned u = __float_as_uint(f);
  return (u16)((u + 0x7fffu + ((u>>16)&1u))>>16); }

// ---------------- K0: weight prep (+ zero the InstanceNorm accumulator) ----------------
// wdcb: deform weights fragment-ordered: idx = (((r*18+s)*8 + f)*64 + l)*8 + e
// wob: off weights fragment-ordered:     idx = ((ntl*36 + s)*64 + l)*8 + e
__global__ __launch_bounds__(256) void prep_weights(const float* __restrict__ pw_w,
    const float* __restrict__ off_w, const float* __restrict__ dc_w,
    u16* __restrict__ wpwb, u16* __restrict__ wob, u16* __restrict__ wdcb,
    float* __restrict__ st2){
  int t = blockIdx.x*256 + threadIdx.x;
  if (t < 1024) st2[t] = 0.f;                 // re-zeroed every launch (stream-ordered)
  if (t < 16384) wpwb[t] = f2b(pw_w[t]);
  if (t < 36864){
    int ntl = t/18432, rem = t - ntl*18432;
    int s = rem>>9, l = (rem>>3)&63, e = rem&7;
    int o = ntl*16 + (l&15);
    int c = (s&3)*32 + ((l>>4)<<3) + e;
    int k = s>>2;
    wob[t] = (o<18) ? f2b(off_w[(o*128+c)*9+k]) : (u16)0;
  }
  if (t < 147456){
    int e = t&7, l = (t>>3)&63, f = (t>>9)&7, g = t>>12;   // g in [0,36)
    int s = g%18, r = g/18;
    int nt = f>>1, ks = f&1;
    int c = ((s&1)<<6) + ks*32 + ((l>>4)<<3) + e;
    int o = (r<<6) + nt*16 + (l&15);
    int k = s>>1;
    wdcb[t] = f2b(dc_w[(o*128+c)*9 + k]);
  }
}

// ---------------- K1: depthwise 3x3 + bias, 4 px/thread, bf16 output ----------------
__global__ __launch_bounds__(256) void dw_conv(const float* __restrict__ x,
    const float* __restrict__ w, const float* __restrict__ bias, u16* __restrict__ h1b){
  int n = blockIdx.x*256 + threadIdx.x;
  int bc = rfl(n / 2304);
  int qp = n - bc*2304;
  int p = qp*4;
  int c = bc & 127;
  int yy = p / WD, xx = p - yy*WD;
  const float* xc = x + (size_t)bc*HW;
  const float* wc = w + c*9;
  float bs = bias[c];
  float a0=bs, a1=bs, a2=bs, a3=bs;
  #pragma unroll
  for (int r=0;r<3;r++){
    int y2 = yy + r - 1;
    if (y2>=0 && y2<96){
      const float* row = xc + y2*WD + xx;
      float4 vc = *(const float4*)row;
      float vl = (xx>0)  ? row[-1] : 0.f;
      float vr = (xx<92) ? row[4]  : 0.f;
      float w0 = wc[r*3+0], w1 = wc[r*3+1], w2 = wc[r*3+2];
      a0 = fmaf(w0, vl,   fmaf(w1, vc.x, fmaf(w2, vc.y, a0)));
      a1 = fmaf(w0, vc.x, fmaf(w1, vc.y, fmaf(w2, vc.z, a1)));
      a2 = fmaf(w0, vc.y, fmaf(w1, vc.z, fmaf(w2, vc.w, a2)));
      a3 = fmaf(w0, vc.z, fmaf(w1, vc.w, fmaf(w2, vr,   a3)));
    }
  }
  ushort4 pk = make_ushort4(f2b(a0), f2b(a1), f2b(a2), f2b(a3));
  *(ushort4*)(h1b + (size_t)bc*HW + p) = pk;
}

// ---------------- K2: pointwise 1x1 via MFMA + fused InstanceNorm partial stats -------
// h2 now stored bf16. Per-channel s/ss computed from fp32 accumulators (pre-round),
// reduced over ln-lanes (shfl_xor bits 0-3), cross-wave via LDS, 2 atomicAdds/channel.
__global__ __launch_bounds__(256) void pw_mfma(const u16* __restrict__ h1b,
    const u16* __restrict__ wpwb, const float* __restrict__ pw_b,
    u16* __restrict__ h2b, float* __restrict__ st2){
  __shared__ short Aw[128*136];
  __shared__ short Bw[128*68];
  __shared__ float PS[4][128], PSS[4][128];
  int blk = blockIdx.x; int row0 = blk*64;
  int b = rfl(row0/HW); int pbase = rfl(row0 - b*HW);
  int t = threadIdx.x;
  #pragma unroll
  for (int i=0;i<8;i++){
    int idx = i*256 + t; int o = idx>>4, seg = idx&15;
    *(short8*)&Aw[o*136 + seg*8] = *(const short8*)(wpwb + o*128 + seg*8);
  }
  #pragma unroll
  for (int i=0;i<4;i++){
    int idx = i*256 + t; int c = idx>>3, seg = idx&7;
    *(short8*)&Bw[c*68 + seg*8] =
      *(const short8*)(h1b + (size_t)(b*NC+c)*HW + pbase + seg*8);
  }
  __syncthreads();
  int w = rfl(t>>6); int l = t&63; int q = l>>4; int ln = l&15;
  v4f acc[8];
  #pragma unroll
  for (int mt=0;mt<8;mt++) acc[mt] = (v4f){0.f,0.f,0.f,0.f};
  #pragma unroll
  for (int ks=0;ks<4;ks++){
    short8 bf;
    #pragma unroll
    for (int j=0;j<8;j++) bf[j] = Bw[(ks*32 + q*8 + j)*68 + w*16 + ln];
    #pragma unroll
    for (int mt=0;mt<8;mt++){
      short8 af = *(short8*)&Aw[(mt*16+ln)*136 + ks*32 + q*8];
      acc[mt] = __builtin_amdgcn_mfma_f32_16x16x32_bf16(af, bf, acc[mt], 0,0,0);
    }
  }
  int px = pbase + w*16 + ln;
  #pragma unroll
  for (int mt=0;mt<8;mt++){
    float sv[4], ssv[4];
    #pragma unroll
    for (int r=0;r<4;r++){
      int o = mt*16 + q*4 + r;
      float v = acc[mt][r] + pw_b[o];
      h2b[(size_t)(b*NC+o)*HW + px] = f2b(v);
      sv[r] = v; ssv[r] = v*v;
    }
    #pragma unroll
    for (int off=1; off<16; off<<=1){
      #pragma unroll
      for (int r=0;r<4;r++){ sv[r] += __shfl_xor(sv[r],off); ssv[r] += __shfl_xor(ssv[r],off); }
    }
    if (ln==0){
      #pragma unroll
      for (int r=0;r<4;r++){ PS[w][mt*16+q*4+r] = sv[r]; PSS[w][mt*16+q*4+r] = ssv[r]; }
    }
  }
  __syncthreads();
  if (t < 128){
    int o = t;
    float S  = PS[0][o]+PS[1][o]+PS[2][o]+PS[3][o];
    float SS = PSS[0][o]+PSS[1][o]+PSS[2][o]+PSS[3][o];
    atomicAdd(&st2[(b*128+o)*2],   S);
    atomicAdd(&st2[(b*128+o)*2+1], SS);
  }
}

// ---------------- K4: dscT (NHWC bf16) from bf16 h2 + accumulated stats ---------------
__global__ __launch_bounds__(256) void make_dsc(const u16* __restrict__ h2b,
    const float* __restrict__ st2, u16* __restrict__ dscT){
  int blk = blockIdx.x;
  int pt = blk % 144; int r = blk/144; int ch = r & 1; int b = r >> 1;
  int c0 = ch*64, pbase = pt*64;
  __shared__ float tile[64][65];
  int tr = threadIdx.x >> 2;
  int g  = threadIdx.x & 3;
  int c  = c0 + tr;
  float S  = st2[(b*128+c)*2];
  float SS = st2[(b*128+c)*2+1];
  float mu = S * (1.f/9216.f);
  float var = SS * (1.f/9216.f) - mu*mu;
  float rs = rsqrtf(var + 1e-5f);
  const u16* src = h2b + (size_t)(b*128+c)*HW + pbase + g*16;
  #pragma unroll
  for (int i=0;i<2;i++){
    short8 v8 = *(const short8*)(src + i*8);
    #pragma unroll
    for (int j=0;j<8;j++){
      float v = (bu2f((u16)v8[j]) - mu)*rs;
      tile[tr][g*16 + i*8 + j] = v;
    }
  }
  __syncthreads();
  int pr = tr;
  u16* dt = dscT + ((size_t)b*HW + pbase + pr)*NC + c0 + g*16;
  #pragma unroll
  for (int i=0;i<4;i++){
    float v0 = tile[g*16+i*4+0][pr], v1 = tile[g*16+i*4+1][pr];
    float v2 = tile[g*16+i*4+2][pr], v3 = tile[g*16+i*4+3][pr];
    ushort4 hi = make_ushort4(f2b(v0), f2b(v1), f2b(v2), f2b(v3));
    *(ushort4*)(dt + i*4) = hi;
  }
}

// ---------------- K5: offset conv, hi-only gather (round 16, unchanged) ---------------
__global__ __launch_bounds__(256) void off_mfma(const u16* __restrict__ dscT,
    const u16* __restrict__ wobp, const float* __restrict__ off_b,
    float4* __restrict__ wg, ushort4* __restrict__ ad){
  __shared__ short As[2][32*40];             // [buf][32px x 32K]
  __shared__ float Po[18*32];
  int blk = blockIdx.x;                      // 1152 = 8 * 144
  int tile = (blk&7)*144 + (blk>>3);
  int row0 = tile*32;
  int b = rfl(row0/HW); int pbase = rfl(row0 - b*HW);
  int t = threadIdx.x;
  bool stg = t < 128;
  int apx = (t>>2)&31, segA = t&3;
  int w = rfl(t>>6); int l = t&63; int q = l>>4; int ln = l&15;
  int mt = w&1, ntl = w>>1;
  int P = pbase + apx;
  int py = P/96, px_ = P - 96*py;
  const u16* gsrc = dscT + (size_t)b*HW*NC;
  const u16* wbase = wobp + ntl*18432 + l*8;
  uint4 rgA, rgB; short8 bregE, bregO;
  auto issue = [&](int s, uint4& rg){
    int k = s>>2, cseg = s&3;
    int y2 = py + k/3 - 1, x2 = px_ + k%3 - 1;
    bool valid = stg && ((unsigned)y2 < 96u) && ((unsigned)x2 < 96u);
    int off = ((y2*96 + x2)*NC) + cseg*32 + segA*8;
    rg = valid ? *(const uint4*)(gsrc + off) : (uint4){0,0,0,0};
  };
  auto issueB = [&](int s)->short8{
    return *(const short8*)(wbase + s*512);
  };
  auto commit = [&](int buf, uint4& rg){
    if (stg) *(short8*)&As[buf][apx*40 + segA*8] = *(short8*)&rg;
  };
  v4f acc = (v4f){0.f,0.f,0.f,0.f};
  auto step = [&](int buf, short8 bf){
    short8 ah = *(short8*)&As[buf][(mt*16+ln)*40 + q*8];
    acc = __builtin_amdgcn_mfma_f32_16x16x32_bf16(ah, bf, acc, 0,0,0);
  };
  issue(0, rgA); issue(1, rgB);
  bregE = issueB(0); bregO = issueB(1);
  commit(0, rgA);
  __syncthreads();
  #pragma unroll 1
  for (int s=0;s<36;s+=2){
    if (s+2<36) issue(s+2, rgA);
    commit(1, rgB);
    step(0, bregE);
    if (s+2<36) bregE = issueB(s+2);
    __syncthreads();
    if (s+3<36) issue(s+3, rgB);
    if (s+2<36) commit(0, rgA);
    step(1, bregO);
    if (s+3<36) bregO = issueB(s+3);
    __syncthreads();
  }
  int o = ntl*16 + ln;
  if (o < 18){
    float ob = off_b[o];
    #pragma unroll
    for (int r=0;r<4;r++) Po[o*32 + mt*16 + q*4 + r] = acc[r] + ob;
  }
  __syncthreads();
  #pragma unroll
  for (int i=0;i<2;i++){
    int idx = i*256 + t;
    if (idx < 288){
      int pxl = idx & 31, k = idx >> 5;
      int Pp = pbase + pxl;
      float dy = Po[(2*k)*32 + pxl], dx = Po[(2*k+1)*32 + pxl];
      float ys = (float)(Pp/96 + k/3 - 1) + dy;
      float xs = (float)(Pp%96 + k%3 - 1) + dx;
      float fy0 = floorf(ys), fx0 = floorf(xs);
      float wy = ys - fy0, wx = xs - fx0;
      int y0 = (int)fy0, x0 = (int)fx0;
      int y1 = y0+1, x1 = x0+1;
      float vy0 = (y0>=0 && y0<=95) ? 1.f : 0.f;
      float vy1 = (y1>=0 && y1<=95) ? 1.f : 0.f;
      float vx0 = (x0>=0 && x0<=95) ? 1.f : 0.f;
      float vx1 = (x1>=0 && x1<=95) ? 1.f : 0.f;
      int y0c=min(max(y0,0),95), y1c=min(max(y1,0),95);
      int x0c=min(max(x0,0),95), x1c=min(max(x1,0),95);
      float4 w4;
      w4.x = (1.f-wy)*(1.f-wx)*vy0*vx0;
      w4.y = (1.f-wy)*wx*vy0*vx1;
      w4.z = wy*(1.f-wx)*vy1*vx0;
      w4.w = wy*wx*vy1*vx1;
      int gi = (b*9 + k)*HW + pbase + pxl;
      wg[gi] = w4;
      ad[gi] = make_ushort4((u16)(y0c*WD+x0c), (u16)(y0c*WD+x1c),
                            (u16)(y1c*WD+x0c), (u16)(y1c*WD+x1c));
    }
  }
}

// ---------------- K6: deform conv + fused epilogue (round 16, unchanged) --------------
__global__ __launch_bounds__(256) void deform_mfma(const u16* __restrict__ dscT,
    const u16* __restrict__ wdcb, const float* __restrict__ dc_b,
    const float4* __restrict__ wg, const ushort4* __restrict__ ad,
    const float* __restrict__ ln_g, const float* __restrict__ ln_b,
    float* __restrict__ out){
  __shared__ short As[2][32*68];
  __shared__ float4 WgL[288];
  __shared__ ushort4 AdL[288];
  __shared__ float RS[2][4][4][4];
  __shared__ u16 DT[32*128];                 // dscT tile for the gate multiply
  int blk = blockIdx.x;                      // 1152 = 8 * 144
  int tile = (blk&7)*144 + (blk>>3);
  int row0 = tile*32;
  int b = rfl(row0/HW); int pbase = rfl(row0 - b*HW);
  int t = threadIdx.x;
  int apx = t>>3, cs8 = t&7;
  int w = rfl(t>>6); int l = t&63; int q = l>>4; int ln = l&15;
  int mt = w&1, nb = (w>>1)*4, rrole = rfl(w>>1);
  const u16* db0 = dscT + (size_t)b*HW*NC + cs8*8;
  const u16* wbase = wdcb + (size_t)rrole*(18*4096) + l*8;
  #pragma unroll
  for (int i=0;i<2;i++){
    int idx = i*256 + t;
    if (idx < 288){ int k = idx>>5, pxl = idx&31; int gi = (b*9+k)*HW + pbase + pxl;
      WgL[idx] = wg[gi]; AdL[idx] = ad[gi]; }
  }
  __syncthreads();
  uint4 gA0,gA1,gA2,gA3, gB0,gB1,gB2,gB3;
  float4 wvA, wvB;
  short8 bregE[8], bregO[8];
  auto issueG = [&](int s, float4& wv, uint4& r0, uint4& r1, uint4& r2, uint4& r3){
    int k = s>>1, cb = (s&1)<<6;
    ushort4 av = AdL[k*32+apx]; wv = WgL[k*32+apx];
    const u16* db = db0 + cb;
    r0 = *(const uint4*)(db + (int)av.x*NC);
    r1 = *(const uint4*)(db + (int)av.y*NC);
    r2 = *(const uint4*)(db + (int)av.z*NC);
    r3 = *(const uint4*)(db + (int)av.w*NC);
  };
  auto issueB = [&](int s, short8* dst){
    const u16* p = wbase + s*4096;
    #pragma unroll
    for (int f=0;f<8;f++) dst[f] = *(const short8*)(p + f*512);
  };
  auto commitA = [&](int buf, float4 wv, uint4& r0, uint4& r1, uint4& r2, uint4& r3){
    const u16* pa=(const u16*)&r0; const u16* pb=(const u16*)&r1;
    const u16* pc=(const u16*)&r2; const u16* pd=(const u16*)&r3;
    short8 sv;
    #pragma unroll
    for (int j=0;j<8;j++){
      float f = wv.x*bu2f(pa[j]) + wv.y*bu2f(pb[j]) + wv.z*bu2f(pc[j]) + wv.w*bu2f(pd[j]);
      sv[j] = (short)f2b(f);
    }
    *(short8*)&As[buf][apx*68 + cs8*8] = sv;
  };
  v4f acc[4];
  #pragma unroll
  for (int nt=0;nt<4;nt++) acc[nt] = (v4f){0.f,0.f,0.f,0.f};
  auto step = [&](int buf, const short8* bb){
    #pragma unroll
    for (int ks=0;ks<2;ks++){
      short8 af = *(const short8*)&As[buf][(mt*16+ln)*68 + ks*32 + q*8];
      #pragma unroll
      for (int nt=0;nt<4;nt++)
        acc[nt] = __builtin_amdgcn_mfma_f32_16x16x32_bf16(af, bb[nt*2+ks], acc[nt], 0,0,0);
    }
  };
  issueG(0, wvA, gA0,gA1,gA2,gA3); issueB(0, bregE);
  issueG(1, wvB, gB0,gB1,gB2,gB3); issueB(1, bregO);
  commitA(0, wvA, gA0,gA1,gA2,gA3);
  __syncthreads();
  #pragma unroll 1
  for (int s=0;s<18;s+=2){
    if (s+2<18) issueG(s+2, wvA, gA0,gA1,gA2,gA3);
    commitA(1, wvB, gB0,gB1,gB2,gB3);
    step(0, bregE);
    if (s+2<18) issueB(s+2, bregE);
    __syncthreads();
    if (s+3<18) issueG(s+3, wvB, gB0,gB1,gB2,gB3);
    if (s+2<18) commitA(0, wvA, gA0,gA1,gA2,gA3);
    step(1, bregO);
    if (s+3<18) issueB(s+3, bregO);
    __syncthreads();
  }
  // ---- fused epilogue ----
  int o_[4]; float bias_[4], g_[4], bb_[4];
  #pragma unroll
  for (int nt=0;nt<4;nt++){
    int o = (nb+nt)*16 + ln;
    o_[nt] = o; bias_[nt] = dc_b[o]; g_[nt] = ln_g[o]; bb_[nt] = ln_b[o];
  }
  float s_[4] = {0.f,0.f,0.f,0.f}, ss_[4] = {0.f,0.f,0.f,0.f};
  #pragma unroll
  for (int r=0;r<4;r++){
    #pragma unroll
    for (int nt=0;nt<4;nt++){
      float v = acc[nt][r] + bias_[nt];
      s_[r] += v; ss_[r] = fmaf(v, v, ss_[r]);
    }
  }
  #pragma unroll
  for (int off=1; off<16; off<<=1){
    #pragma unroll
    for (int r=0;r<4;r++){
      s_[r]  += __shfl_xor(s_[r],  off);
      ss_[r] += __shfl_xor(ss_[r], off);
    }
  }
  if (ln==0){
    #pragma unroll
    for (int r=0;r<4;r++){ RS[0][w][q][r] = s_[r]; RS[1][w][q][r] = ss_[r]; }
  }
  // stage the block's dscT tile (contiguous 32*128 u16 = 8KB) for the gate multiply
  {
    const u16* dsrc = dscT + ((size_t)b*HW + pbase)*NC;
    #pragma unroll
    for (int i=0;i<2;i++){
      int idx = i*256 + t;
      *(short8*)&DT[idx*8] = *(const short8*)(dsrc + idx*8);
    }
  }
  __syncthreads();
  float m_[4], rs_[4];
  #pragma unroll
  for (int r=0;r<4;r++){
    float S  = RS[0][w][q][r] + RS[0][w^2][q][r];
    float SS = RS[1][w][q][r] + RS[1][w^2][q][r];
    float m = S*(1.f/128.f);
    float var = SS*(1.f/128.f) - m*m;
    m_[r] = m; rs_[r] = rsqrtf(var + 1e-5f);
  }
  int pxb = pbase + mt*16 + q*4;
  int lpx = mt*16 + q*4;
  #pragma unroll
  for (int nt=0;nt<4;nt++){
    size_t base = (size_t)(b*NC + o_[nt])*HW + pxb;
    float4 ov;
    #pragma unroll
    for (int r=0;r<4;r++){
      float v = acc[nt][r] + bias_[nt];
      float lnv = (v - m_[r])*rs_[r]*g_[nt] + bb_[nt];
      float attn = 1.f/(1.f+__expf(-lnv));
      float dv = bu2f(DT[(lpx+r)*128 + o_[nt]]);
      ((float*)&ov)[r] = dv * attn;
    }
    *(float4*)(out + base) = ov;
  }
}

extern "C" void kernel_launch(void* const* d_in, const int* in_sizes, int n_in,
                              void* d_out, int out_size, void* d_ws, size_t ws_size,
                              hipStream_t stream){
  const float* x    = (const float*)d_in[0];
  const float* dw_w = (const float*)d_in[1];
  const float* dw_b = (const float*)d_in[2];
  const float* pw_w = (const float*)d_in[3];
  const float* pw_b = (const float*)d_in[4];
  const float* off_w= (const float*)d_in[5];
  const float* off_b= (const float*)d_in[6];
  const float* dc_w = (const float*)d_in[7];
  const float* dc_b = (const float*)d_in[8];
  const float* ln_g = (const float*)d_in[9];
  const float* ln_b = (const float*)d_in[10];
  float* out = (float*)d_out;

  float* W    = (float*)d_ws;
  u16*     h1b  = (u16*)W;                    // h1 bf16
  u16*     h2b  = (u16*)(W + 4718592);        // h2 bf16
  u16*     dscT = (u16*)(W + 9437184);        // NHWC bf16
  float4*  wg   = (float4*)(W + 14155776);    // 331776 float4
  ushort4* ad   = (ushort4*)(W + 15482880);   // 331776 ushort4
  float*   st2  = W + 16146432;               // 1024 floats (S,SS per b,c)
  u16*     wpwb = (u16*)(W + 16147456);       // 16384 u16
  u16*     wob  = (u16*)(W + 16155648);       // 36864 u16 (fragment-permuted)
  u16*     wdcb = (u16*)(W + 16174080);       // 147456 u16 (fragment-permuted)

  prep_weights<<<576, 256, 0, stream>>>(pw_w, off_w, dc_w, wpwb, wob, wdcb, st2);
  dw_conv     <<<4608, 256, 0, stream>>>(x, dw_w, dw_b, h1b);
  pw_mfma     <<<576, 256, 0, stream>>>(h1b, wpwb, pw_b, h2b, st2);
  make_dsc    <<<1152, 256, 0, stream>>>(h2b, st2, dscT);
  off_mfma    <<<1152, 256, 0, stream>>>(dscT, wob, off_b, wg, ad);
  deform_mfma <<<1152, 256, 0, stream>>>(dscT, wdcb, dc_b, wg, ad, ln_g, ln_b, out);
}

// Round 18
// 171.782 us; speedup vs baseline: 1.0741x; 1.0741x over previous
//
#include <hip/hip_runtime.h>
#include <math.h>

#define HW 9216
#define WD 96
#define NC 128

typedef unsigned short u16;
typedef __attribute__((ext_vector_type(8))) short short8;
typedef __attribute__((ext_vector_type(4))) float v4f;

__device__ __forceinline__ int rfl(int v){ return __builtin_amdgcn_readfirstlane(v); }
__device__ __forceinline__ float bu2f(u16 s){ return __uint_as_float(((unsigned)s)<<16); }
__device__ __forceinline__ u16 f2b(float f){ unsigned u = __float_as_uint(f);
  return (u16)((u + 0x7fffu + ((u>>16)&1u))>>16); }

// ---------------- K0: weight prep ----------------
// wdcb: deform weights fragment-ordered: idx = (((r*18+s)*8 + f)*64 + l)*8 + e
// wob: off weights fragment-ordered:     idx = ((ntl*36 + s)*64 + l)*8 + e
__global__ __launch_bounds__(256) void prep_weights(const float* __restrict__ pw_w,
    const float* __restrict__ off_w, const float* __restrict__ dc_w,
    u16* __restrict__ wpwb, u16* __restrict__ wob, u16* __restrict__ wdcb){
  int t = blockIdx.x*256 + threadIdx.x;
  if (t < 16384) wpwb[t] = f2b(pw_w[t]);
  if (t < 36864){
    int ntl = t/18432, rem = t - ntl*18432;
    int s = rem>>9, l = (rem>>3)&63, e = rem&7;
    int o = ntl*16 + (l&15);
    int c = (s&3)*32 + ((l>>4)<<3) + e;
    int k = s>>2;
    wob[t] = (o<18) ? f2b(off_w[(o*128+c)*9+k]) : (u16)0;
  }
  if (t < 147456){
    int e = t&7, l = (t>>3)&63, f = (t>>9)&7, g = t>>12;   // g in [0,36)
    int s = g%18, r = g/18;
    int nt = f>>1, ks = f&1;
    int c = ((s&1)<<6) + ks*32 + ((l>>4)<<3) + e;
    int o = (r<<6) + nt*16 + (l&15);
    int k = s>>1;
    wdcb[t] = f2b(dc_w[(o*128+c)*9 + k]);
  }
}

// ---------------- K1: depthwise 3x3 + bias, 4 px/thread, bf16 output ----------------
__global__ __launch_bounds__(256) void dw_conv(const float* __restrict__ x,
    const float* __restrict__ w, const float* __restrict__ bias, u16* __restrict__ h1b){
  int n = blockIdx.x*256 + threadIdx.x;
  int bc = rfl(n / 2304);
  int qp = n - bc*2304;
  int p = qp*4;
  int c = bc & 127;
  int yy = p / WD, xx = p - yy*WD;
  const float* xc = x + (size_t)bc*HW;
  const float* wc = w + c*9;
  float bs = bias[c];
  float a0=bs, a1=bs, a2=bs, a3=bs;
  #pragma unroll
  for (int r=0;r<3;r++){
    int y2 = yy + r - 1;
    if (y2>=0 && y2<96){
      const float* row = xc + y2*WD + xx;
      float4 vc = *(const float4*)row;
      float vl = (xx>0)  ? row[-1] : 0.f;
      float vr = (xx<92) ? row[4]  : 0.f;
      float w0 = wc[r*3+0], w1 = wc[r*3+1], w2 = wc[r*3+2];
      a0 = fmaf(w0, vl,   fmaf(w1, vc.x, fmaf(w2, vc.y, a0)));
      a1 = fmaf(w0, vc.x, fmaf(w1, vc.y, fmaf(w2, vc.z, a1)));
      a2 = fmaf(w0, vc.y, fmaf(w1, vc.z, fmaf(w2, vc.w, a2)));
      a3 = fmaf(w0, vc.z, fmaf(w1, vc.w, fmaf(w2, vr,   a3)));
    }
  }
  ushort4 pk = make_ushort4(f2b(a0), f2b(a1), f2b(a2), f2b(a3));
  *(ushort4*)(h1b + (size_t)bc*HW + p) = pk;
}

// ---------------- K2: pointwise 1x1 via MFMA (round-16 compute, bf16 h2 store) --------
__global__ __launch_bounds__(256) void pw_mfma(const u16* __restrict__ h1b,
    const u16* __restrict__ wpwb, const float* __restrict__ pw_b,
    u16* __restrict__ h2b){
  __shared__ short Aw[128*136];
  __shared__ short Bw[128*68];
  int blk = blockIdx.x; int row0 = blk*64;
  int b = rfl(row0/HW); int pbase = rfl(row0 - b*HW);
  int t = threadIdx.x;
  #pragma unroll
  for (int i=0;i<8;i++){
    int idx = i*256 + t; int o = idx>>4, seg = idx&15;
    *(short8*)&Aw[o*136 + seg*8] = *(const short8*)(wpwb + o*128 + seg*8);
  }
  #pragma unroll
  for (int i=0;i<4;i++){
    int idx = i*256 + t; int c = idx>>3, seg = idx&7;
    *(short8*)&Bw[c*68 + seg*8] =
      *(const short8*)(h1b + (size_t)(b*NC+c)*HW + pbase + seg*8);
  }
  __syncthreads();
  int w = rfl(t>>6); int l = t&63; int q = l>>4; int ln = l&15;
  v4f acc[8];
  #pragma unroll
  for (int mt=0;mt<8;mt++) acc[mt] = (v4f){0.f,0.f,0.f,0.f};
  #pragma unroll
  for (int ks=0;ks<4;ks++){
    short8 bf;
    #pragma unroll
    for (int j=0;j<8;j++) bf[j] = Bw[(ks*32 + q*8 + j)*68 + w*16 + ln];
    #pragma unroll
    for (int mt=0;mt<8;mt++){
      short8 af = *(short8*)&Aw[(mt*16+ln)*136 + ks*32 + q*8];
      acc[mt] = __builtin_amdgcn_mfma_f32_16x16x32_bf16(af, bf, acc[mt], 0,0,0);
    }
  }
  int px = pbase + w*16 + ln;
  #pragma unroll
  for (int mt=0;mt<8;mt++){
    #pragma unroll
    for (int r=0;r<4;r++){
      int o = mt*16 + q*4 + r;
      h2b[(size_t)(b*NC+o)*HW + px] = f2b(acc[mt][r] + pw_b[o]);
    }
  }
}

// ---------------- K3: InstanceNorm stats (bf16 h2, short8 reads) ----------------
__global__ __launch_bounds__(256) void inorm_stats(const u16* __restrict__ h2b,
    float* __restrict__ st){
  int bc = blockIdx.x;
  const u16* src = h2b + (size_t)bc*HW;
  float s=0.f, ss=0.f;
  for (int i=threadIdx.x; i<1152; i+=256){
    short8 v8 = *(const short8*)(src + i*8);
    #pragma unroll
    for (int j=0;j<8;j++){
      float v = bu2f((u16)v8[j]);
      s += v; ss = fmaf(v,v,ss);
    }
  }
  #pragma unroll
  for (int off=32; off; off>>=1){ s += __shfl_down(s,off); ss += __shfl_down(ss,off); }
  __shared__ float rsm[2][4];
  int wave = threadIdx.x>>6, lane = threadIdx.x&63;
  if (lane==0){ rsm[0][wave]=s; rsm[1][wave]=ss; }
  __syncthreads();
  if (threadIdx.x==0){
    float S = rsm[0][0]+rsm[0][1]+rsm[0][2]+rsm[0][3];
    float SS= rsm[1][0]+rsm[1][1]+rsm[1][2]+rsm[1][3];
    float mu = S * (1.f/9216.f);
    float var = SS * (1.f/9216.f) - mu*mu;
    st[bc*2]   = mu;
    st[bc*2+1] = rsqrtf(var + 1e-5f);
  }
}

// ---------------- K4: dscT (NHWC bf16) from bf16 h2 + (mu, rs) ----------------
__global__ __launch_bounds__(256) void make_dsc(const u16* __restrict__ h2b,
    const float* __restrict__ st, u16* __restrict__ dscT){
  int blk = blockIdx.x;
  int pt = blk % 144; int r = blk/144; int ch = r & 1; int b = r >> 1;
  int c0 = ch*64, pbase = pt*64;
  __shared__ float tile[64][65];
  int tr = threadIdx.x >> 2;
  int g  = threadIdx.x & 3;
  int c  = c0 + tr;
  float mu = st[(b*128+c)*2];
  float rs = st[(b*128+c)*2+1];
  const u16* src = h2b + (size_t)(b*128+c)*HW + pbase + g*16;
  #pragma unroll
  for (int i=0;i<2;i++){
    short8 v8 = *(const short8*)(src + i*8);
    #pragma unroll
    for (int j=0;j<8;j++){
      float v = (bu2f((u16)v8[j]) - mu)*rs;
      tile[tr][g*16 + i*8 + j] = v;
    }
  }
  __syncthreads();
  int pr = tr;
  u16* dt = dscT + ((size_t)b*HW + pbase + pr)*NC + c0 + g*16;
  #pragma unroll
  for (int i=0;i<4;i++){
    float v0 = tile[g*16+i*4+0][pr], v1 = tile[g*16+i*4+1][pr];
    float v2 = tile[g*16+i*4+2][pr], v3 = tile[g*16+i*4+3][pr];
    ushort4 hi = make_ushort4(f2b(v0), f2b(v1), f2b(v2), f2b(v3));
    *(ushort4*)(dt + i*4) = hi;
  }
}

// ---------------- K5: offset conv, hi-only gather (round 16, unchanged) ---------------
__global__ __launch_bounds__(256) void off_mfma(const u16* __restrict__ dscT,
    const u16* __restrict__ wobp, const float* __restrict__ off_b,
    float4* __restrict__ wg, ushort4* __restrict__ ad){
  __shared__ short As[2][32*40];             // [buf][32px x 32K]
  __shared__ float Po[18*32];
  int blk = blockIdx.x;                      // 1152 = 8 * 144
  int tile = (blk&7)*144 + (blk>>3);
  int row0 = tile*32;
  int b = rfl(row0/HW); int pbase = rfl(row0 - b*HW);
  int t = threadIdx.x;
  bool stg = t < 128;
  int apx = (t>>2)&31, segA = t&3;
  int w = rfl(t>>6); int l = t&63; int q = l>>4; int ln = l&15;
  int mt = w&1, ntl = w>>1;
  int P = pbase + apx;
  int py = P/96, px_ = P - 96*py;
  const u16* gsrc = dscT + (size_t)b*HW*NC;
  const u16* wbase = wobp + ntl*18432 + l*8;
  uint4 rgA, rgB; short8 bregE, bregO;
  auto issue = [&](int s, uint4& rg){
    int k = s>>2, cseg = s&3;
    int y2 = py + k/3 - 1, x2 = px_ + k%3 - 1;
    bool valid = stg && ((unsigned)y2 < 96u) && ((unsigned)x2 < 96u);
    int off = ((y2*96 + x2)*NC) + cseg*32 + segA*8;
    rg = valid ? *(const uint4*)(gsrc + off) : (uint4){0,0,0,0};
  };
  auto issueB = [&](int s)->short8{
    return *(const short8*)(wbase + s*512);
  };
  auto commit = [&](int buf, uint4& rg){
    if (stg) *(short8*)&As[buf][apx*40 + segA*8] = *(short8*)&rg;
  };
  v4f acc = (v4f){0.f,0.f,0.f,0.f};
  auto step = [&](int buf, short8 bf){
    short8 ah = *(short8*)&As[buf][(mt*16+ln)*40 + q*8];
    acc = __builtin_amdgcn_mfma_f32_16x16x32_bf16(ah, bf, acc, 0,0,0);
  };
  issue(0, rgA); issue(1, rgB);
  bregE = issueB(0); bregO = issueB(1);
  commit(0, rgA);
  __syncthreads();
  #pragma unroll 1
  for (int s=0;s<36;s+=2){
    if (s+2<36) issue(s+2, rgA);
    commit(1, rgB);
    step(0, bregE);
    if (s+2<36) bregE = issueB(s+2);
    __syncthreads();
    if (s+3<36) issue(s+3, rgB);
    if (s+2<36) commit(0, rgA);
    step(1, bregO);
    if (s+3<36) bregO = issueB(s+3);
    __syncthreads();
  }
  int o = ntl*16 + ln;
  if (o < 18){
    float ob = off_b[o];
    #pragma unroll
    for (int r=0;r<4;r++) Po[o*32 + mt*16 + q*4 + r] = acc[r] + ob;
  }
  __syncthreads();
  #pragma unroll
  for (int i=0;i<2;i++){
    int idx = i*256 + t;
    if (idx < 288){
      int pxl = idx & 31, k = idx >> 5;
      int Pp = pbase + pxl;
      float dy = Po[(2*k)*32 + pxl], dx = Po[(2*k+1)*32 + pxl];
      float ys = (float)(Pp/96 + k/3 - 1) + dy;
      float xs = (float)(Pp%96 + k%3 - 1) + dx;
      float fy0 = floorf(ys), fx0 = floorf(xs);
      float wy = ys - fy0, wx = xs - fx0;
      int y0 = (int)fy0, x0 = (int)fx0;
      int y1 = y0+1, x1 = x0+1;
      float vy0 = (y0>=0 && y0<=95) ? 1.f : 0.f;
      float vy1 = (y1>=0 && y1<=95) ? 1.f : 0.f;
      float vx0 = (x0>=0 && x0<=95) ? 1.f : 0.f;
      float vx1 = (x1>=0 && x1<=95) ? 1.f : 0.f;
      int y0c=min(max(y0,0),95), y1c=min(max(y1,0),95);
      int x0c=min(max(x0,0),95), x1c=min(max(x1,0),95);
      float4 w4;
      w4.x = (1.f-wy)*(1.f-wx)*vy0*vx0;
      w4.y = (1.f-wy)*wx*vy0*vx1;
      w4.z = wy*(1.f-wx)*vy1*vx0;
      w4.w = wy*wx*vy1*vx1;
      int gi = (b*9 + k)*HW + pbase + pxl;
      wg[gi] = w4;
      ad[gi] = make_ushort4((u16)(y0c*WD+x0c), (u16)(y0c*WD+x1c),
                            (u16)(y1c*WD+x0c), (u16)(y1c*WD+x1c));
    }
  }
}

// ---------------- K6: deform conv + fused epilogue (round 16, unchanged) --------------
__global__ __launch_bounds__(256) void deform_mfma(const u16* __restrict__ dscT,
    const u16* __restrict__ wdcb, const float* __restrict__ dc_b,
    const float4* __restrict__ wg, const ushort4* __restrict__ ad,
    const float* __restrict__ ln_g, const float* __restrict__ ln_b,
    float* __restrict__ out){
  __shared__ short As[2][32*68];
  __shared__ float4 WgL[288];
  __shared__ ushort4 AdL[288];
  __shared__ float RS[2][4][4][4];
  __shared__ u16 DT[32*128];                 // dscT tile for the gate multiply
  int blk = blockIdx.x;                      // 1152 = 8 * 144
  int tile = (blk&7)*144 + (blk>>3);
  int row0 = tile*32;
  int b = rfl(row0/HW); int pbase = rfl(row0 - b*HW);
  int t = threadIdx.x;
  int apx = t>>3, cs8 = t&7;
  int w = rfl(t>>6); int l = t&63; int q = l>>4; int ln = l&15;
  int mt = w&1, nb = (w>>1)*4, rrole = rfl(w>>1);
  const u16* db0 = dscT + (size_t)b*HW*NC + cs8*8;
  const u16* wbase = wdcb + (size_t)rrole*(18*4096) + l*8;
  #pragma unroll
  for (int i=0;i<2;i++){
    int idx = i*256 + t;
    if (idx < 288){ int k = idx>>5, pxl = idx&31; int gi = (b*9+k)*HW + pbase + pxl;
      WgL[idx] = wg[gi]; AdL[idx] = ad[gi]; }
  }
  __syncthreads();
  uint4 gA0,gA1,gA2,gA3, gB0,gB1,gB2,gB3;
  float4 wvA, wvB;
  short8 bregE[8], bregO[8];
  auto issueG = [&](int s, float4& wv, uint4& r0, uint4& r1, uint4& r2, uint4& r3){
    int k = s>>1, cb = (s&1)<<6;
    ushort4 av = AdL[k*32+apx]; wv = WgL[k*32+apx];
    const u16* db = db0 + cb;
    r0 = *(const uint4*)(db + (int)av.x*NC);
    r1 = *(const uint4*)(db + (int)av.y*NC);
    r2 = *(const uint4*)(db + (int)av.z*NC);
    r3 = *(const uint4*)(db + (int)av.w*NC);
  };
  auto issueB = [&](int s, short8* dst){
    const u16* p = wbase + s*4096;
    #pragma unroll
    for (int f=0;f<8;f++) dst[f] = *(const short8*)(p + f*512);
  };
  auto commitA = [&](int buf, float4 wv, uint4& r0, uint4& r1, uint4& r2, uint4& r3){
    const u16* pa=(const u16*)&r0; const u16* pb=(const u16*)&r1;
    const u16* pc=(const u16*)&r2; const u16* pd=(const u16*)&r3;
    short8 sv;
    #pragma unroll
    for (int j=0;j<8;j++){
      float f = wv.x*bu2f(pa[j]) + wv.y*bu2f(pb[j]) + wv.z*bu2f(pc[j]) + wv.w*bu2f(pd[j]);
      sv[j] = (short)f2b(f);
    }
    *(short8*)&As[buf][apx*68 + cs8*8] = sv;
  };
  v4f acc[4];
  #pragma unroll
  for (int nt=0;nt<4;nt++) acc[nt] = (v4f){0.f,0.f,0.f,0.f};
  auto step = [&](int buf, const short8* bb){
    #pragma unroll
    for (int ks=0;ks<2;ks++){
      short8 af = *(const short8*)&As[buf][(mt*16+ln)*68 + ks*32 + q*8];
      #pragma unroll
      for (int nt=0;nt<4;nt++)
        acc[nt] = __builtin_amdgcn_mfma_f32_16x16x32_bf16(af, bb[nt*2+ks], acc[nt], 0,0,0);
    }
  };
  issueG(0, wvA, gA0,gA1,gA2,gA3); issueB(0, bregE);
  issueG(1, wvB, gB0,gB1,gB2,gB3); issueB(1, bregO);
  commitA(0, wvA, gA0,gA1,gA2,gA3);
  __syncthreads();
  #pragma unroll 1
  for (int s=0;s<18;s+=2){
    if (s+2<18) issueG(s+2, wvA, gA0,gA1,gA2,gA3);
    commitA(1, wvB, gB0,gB1,gB2,gB3);
    step(0, bregE);
    if (s+2<18) issueB(s+2, bregE);
    __syncthreads();
    if (s+3<18) issueG(s+3, wvB, gB0,gB1,gB2,gB3);
    if (s+2<18) commitA(0, wvA, gA0,gA1,gA2,gA3);
    step(1, bregO);
    if (s+3<18) issueB(s+3, bregO);
    __syncthreads();
  }
  // ---- fused epilogue ----
  int o_[4]; float bias_[4], g_[4], bb_[4];
  #pragma unroll
  for (int nt=0;nt<4;nt++){
    int o = (nb+nt)*16 + ln;
    o_[nt] = o; bias_[nt] = dc_b[o]; g_[nt] = ln_g[o]; bb_[nt] = ln_b[o];
  }
  float s_[4] = {0.f,0.f,0.f,0.f}, ss_[4] = {0.f,0.f,0.f,0.f};
  #pragma unroll
  for (int r=0;r<4;r++){
    #pragma unroll
    for (int nt=0;nt<4;nt++){
      float v = acc[nt][r] + bias_[nt];
      s_[r] += v; ss_[r] = fmaf(v, v, ss_[r]);
    }
  }
  #pragma unroll
  for (int off=1; off<16; off<<=1){
    #pragma unroll
    for (int r=0;r<4;r++){
      s_[r]  += __shfl_xor(s_[r],  off);
      ss_[r] += __shfl_xor(ss_[r], off);
    }
  }
  if (ln==0){
    #pragma unroll
    for (int r=0;r<4;r++){ RS[0][w][q][r] = s_[r]; RS[1][w][q][r] = ss_[r]; }
  }
  // stage the block's dscT tile (contiguous 32*128 u16 = 8KB) for the gate multiply
  {
    const u16* dsrc = dscT + ((size_t)b*HW + pbase)*NC;
    #pragma unroll
    for (int i=0;i<2;i++){
      int idx = i*256 + t;
      *(short8*)&DT[idx*8] = *(const short8*)(dsrc + idx*8);
    }
  }
  __syncthreads();
  float m_[4], rs_[4];
  #pragma unroll
  for (int r=0;r<4;r++){
    float S  = RS[0][w][q][r] + RS[0][w^2][q][r];
    float SS = RS[1][w][q][r] + RS[1][w^2][q][r];
    float m = S*(1.f/128.f);
    float var = SS*(1.f/128.f) - m*m;
    m_[r] = m; rs_[r] = rsqrtf(var + 1e-5f);
  }
  int pxb = pbase + mt*16 + q*4;
  int lpx = mt*16 + q*4;
  #pragma unroll
  for (int nt=0;nt<4;nt++){
    size_t base = (size_t)(b*NC + o_[nt])*HW + pxb;
    float4 ov;
    #pragma unroll
    for (int r=0;r<4;r++){
      float v = acc[nt][r] + bias_[nt];
      float lnv = (v - m_[r])*rs_[r]*g_[nt] + bb_[nt];
      float attn = 1.f/(1.f+__expf(-lnv));
      float dv = bu2f(DT[(lpx+r)*128 + o_[nt]]);
      ((float*)&ov)[r] = dv * attn;
    }
    *(float4*)(out + base) = ov;
  }
}

extern "C" void kernel_launch(void* const* d_in, const int* in_sizes, int n_in,
                              void* d_out, int out_size, void* d_ws, size_t ws_size,
                              hipStream_t stream){
  const float* x    = (const float*)d_in[0];
  const float* dw_w = (const float*)d_in[1];
  const float* dw_b = (const float*)d_in[2];
  const float* pw_w = (const float*)d_in[3];
  const float* pw_b = (const float*)d_in[4];
  const float* off_w= (const float*)d_in[5];
  const float* off_b= (const float*)d_in[6];
  const float* dc_w = (const float*)d_in[7];
  const float* dc_b = (const float*)d_in[8];
  const float* ln_g = (const float*)d_in[9];
  const float* ln_b = (const float*)d_in[10];
  float* out = (float*)d_out;

  float* W    = (float*)d_ws;
  u16*     h1b  = (u16*)W;                    // h1 bf16
  u16*     h2b  = (u16*)(W + 4718592);        // h2 bf16
  u16*     dscT = (u16*)(W + 9437184);        // NHWC bf16
  float4*  wg   = (float4*)(W + 14155776);    // 331776 float4
  ushort4* ad   = (ushort4*)(W + 15482880);   // 331776 ushort4
  float*   st   = W + 16146432;               // 1024 floats (mu, rs per b,c)
  u16*     wpwb = (u16*)(W + 16147456);       // 16384 u16
  u16*     wob  = (u16*)(W + 16155648);       // 36864 u16 (fragment-permuted)
  u16*     wdcb = (u16*)(W + 16174080);       // 147456 u16 (fragment-permuted)

  prep_weights<<<576, 256, 0, stream>>>(pw_w, off_w, dc_w, wpwb, wob, wdcb);
  dw_conv     <<<4608, 256, 0, stream>>>(x, dw_w, dw_b, h1b);
  pw_mfma     <<<576, 256, 0, stream>>>(h1b, wpwb, pw_b, h2b);
  inorm_stats <<<512, 256, 0, stream>>>(h2b, st);
  make_dsc    <<<1152, 256, 0, stream>>>(h2b, st, dscT);
  off_mfma    <<<1152, 256, 0, stream>>>(dscT, wob, off_b, wg, ad);
  deform_mfma <<<1152, 256, 0, stream>>>(dscT, wdcb, dc_b, wg, ad, ln_g, ln_b, out);
}

// Round 19
// 169.184 us; speedup vs baseline: 1.0906x; 1.0154x over previous
//
#include <hip/hip_runtime.h>
#include <math.h>

#define HW 9216
#define WD 96
#define NC 128

typedef unsigned short u16;
typedef __attribute__((ext_vector_type(8))) short short8;
typedef __attribute__((ext_vector_type(4))) float v4f;

__device__ __forceinline__ int rfl(int v){ return __builtin_amdgcn_readfirstlane(v); }
__device__ __forceinline__ float bu2f(u16 s){ return __uint_as_float(((unsigned)s)<<16); }
__device__ __forceinline__ u16 f2b(float f){ unsigned u = __float_as_uint(f);
  return (u16)((u + 0x7fffu + ((u>>16)&1u))>>16); }

// ---------------- K0: weight prep ----------------
// wdcb: deform weights fragment-ordered: idx = (((r*18+s)*8 + f)*64 + l)*8 + e
// wob: off weights fragment-ordered:     idx = ((ntl*36 + s)*64 + l)*8 + e
__global__ __launch_bounds__(256) void prep_weights(const float* __restrict__ pw_w,
    const float* __restrict__ off_w, const float* __restrict__ dc_w,
    u16* __restrict__ wpwb, u16* __restrict__ wob, u16* __restrict__ wdcb){
  int t = blockIdx.x*256 + threadIdx.x;
  if (t < 16384) wpwb[t] = f2b(pw_w[t]);
  if (t < 36864){
    int ntl = t/18432, rem = t - ntl*18432;
    int s = rem>>9, l = (rem>>3)&63, e = rem&7;
    int o = ntl*16 + (l&15);
    int c = (s&3)*32 + ((l>>4)<<3) + e;
    int k = s>>2;
    wob[t] = (o<18) ? f2b(off_w[(o*128+c)*9+k]) : (u16)0;
  }
  if (t < 147456){
    int e = t&7, l = (t>>3)&63, f = (t>>9)&7, g = t>>12;   // g in [0,36)
    int s = g%18, r = g/18;
    int nt = f>>1, ks = f&1;
    int c = ((s&1)<<6) + ks*32 + ((l>>4)<<3) + e;
    int o = (r<<6) + nt*16 + (l&15);
    int k = s>>1;
    wdcb[t] = f2b(dc_w[(o*128+c)*9 + k]);
  }
}

// ---------------- K1: depthwise 3x3 + bias, 4 px/thread, bf16 output ----------------
__global__ __launch_bounds__(256) void dw_conv(const float* __restrict__ x,
    const float* __restrict__ w, const float* __restrict__ bias, u16* __restrict__ h1b){
  int n = blockIdx.x*256 + threadIdx.x;
  int bc = rfl(n / 2304);
  int qp = n - bc*2304;
  int p = qp*4;
  int c = bc & 127;
  int yy = p / WD, xx = p - yy*WD;
  const float* xc = x + (size_t)bc*HW;
  const float* wc = w + c*9;
  float bs = bias[c];
  float a0=bs, a1=bs, a2=bs, a3=bs;
  #pragma unroll
  for (int r=0;r<3;r++){
    int y2 = yy + r - 1;
    if (y2>=0 && y2<96){
      const float* row = xc + y2*WD + xx;
      float4 vc = *(const float4*)row;
      float vl = (xx>0)  ? row[-1] : 0.f;
      float vr = (xx<92) ? row[4]  : 0.f;
      float w0 = wc[r*3+0], w1 = wc[r*3+1], w2 = wc[r*3+2];
      a0 = fmaf(w0, vl,   fmaf(w1, vc.x, fmaf(w2, vc.y, a0)));
      a1 = fmaf(w0, vc.x, fmaf(w1, vc.y, fmaf(w2, vc.z, a1)));
      a2 = fmaf(w0, vc.y, fmaf(w1, vc.z, fmaf(w2, vc.w, a2)));
      a3 = fmaf(w0, vc.z, fmaf(w1, vc.w, fmaf(w2, vr,   a3)));
    }
  }
  ushort4 pk = make_ushort4(f2b(a0), f2b(a1), f2b(a2), f2b(a3));
  *(ushort4*)(h1b + (size_t)bc*HW + p) = pk;
}

// ---------------- K2: pointwise 1x1 via MFMA (bf16 h2 store) ----------------
__global__ __launch_bounds__(256) void pw_mfma(const u16* __restrict__ h1b,
    const u16* __restrict__ wpwb, const float* __restrict__ pw_b,
    u16* __restrict__ h2b){
  __shared__ short Aw[128*136];
  __shared__ short Bw[128*68];
  int blk = blockIdx.x; int row0 = blk*64;
  int b = rfl(row0/HW); int pbase = rfl(row0 - b*HW);
  int t = threadIdx.x;
  #pragma unroll
  for (int i=0;i<8;i++){
    int idx = i*256 + t; int o = idx>>4, seg = idx&15;
    *(short8*)&Aw[o*136 + seg*8] = *(const short8*)(wpwb + o*128 + seg*8);
  }
  #pragma unroll
  for (int i=0;i<4;i++){
    int idx = i*256 + t; int c = idx>>3, seg = idx&7;
    *(short8*)&Bw[c*68 + seg*8] =
      *(const short8*)(h1b + (size_t)(b*NC+c)*HW + pbase + seg*8);
  }
  __syncthreads();
  int w = rfl(t>>6); int l = t&63; int q = l>>4; int ln = l&15;
  v4f acc[8];
  #pragma unroll
  for (int mt=0;mt<8;mt++) acc[mt] = (v4f){0.f,0.f,0.f,0.f};
  #pragma unroll
  for (int ks=0;ks<4;ks++){
    short8 bf;
    #pragma unroll
    for (int j=0;j<8;j++) bf[j] = Bw[(ks*32 + q*8 + j)*68 + w*16 + ln];
    #pragma unroll
    for (int mt=0;mt<8;mt++){
      short8 af = *(short8*)&Aw[(mt*16+ln)*136 + ks*32 + q*8];
      acc[mt] = __builtin_amdgcn_mfma_f32_16x16x32_bf16(af, bf, acc[mt], 0,0,0);
    }
  }
  int px = pbase + w*16 + ln;
  #pragma unroll
  for (int mt=0;mt<8;mt++){
    #pragma unroll
    for (int r=0;r<4;r++){
      int o = mt*16 + q*4 + r;
      h2b[(size_t)(b*NC+o)*HW + px] = f2b(acc[mt][r] + pw_b[o]);
    }
  }
}

// ---------------- K3: InstanceNorm stats (bf16 h2, short8 reads) ----------------
__global__ __launch_bounds__(256) void inorm_stats(const u16* __restrict__ h2b,
    float* __restrict__ st){
  int bc = blockIdx.x;
  const u16* src = h2b + (size_t)bc*HW;
  float s=0.f, ss=0.f;
  for (int i=threadIdx.x; i<1152; i+=256){
    short8 v8 = *(const short8*)(src + i*8);
    #pragma unroll
    for (int j=0;j<8;j++){
      float v = bu2f((u16)v8[j]);
      s += v; ss = fmaf(v,v,ss);
    }
  }
  #pragma unroll
  for (int off=32; off; off>>=1){ s += __shfl_down(s,off); ss += __shfl_down(ss,off); }
  __shared__ float rsm[2][4];
  int wave = threadIdx.x>>6, lane = threadIdx.x&63;
  if (lane==0){ rsm[0][wave]=s; rsm[1][wave]=ss; }
  __syncthreads();
  if (threadIdx.x==0){
    float S = rsm[0][0]+rsm[0][1]+rsm[0][2]+rsm[0][3];
    float SS= rsm[1][0]+rsm[1][1]+rsm[1][2]+rsm[1][3];
    float mu = S * (1.f/9216.f);
    float var = SS * (1.f/9216.f) - mu*mu;
    st[bc*2]   = mu;
    st[bc*2+1] = rsqrtf(var + 1e-5f);
  }
}

// ---------------- K4: dscT (NHWC bf16) from bf16 h2 + (mu, rs) ----------------
__global__ __launch_bounds__(256) void make_dsc(const u16* __restrict__ h2b,
    const float* __restrict__ st, u16* __restrict__ dscT){
  int blk = blockIdx.x;
  int pt = blk % 144; int r = blk/144; int ch = r & 1; int b = r >> 1;
  int c0 = ch*64, pbase = pt*64;
  __shared__ float tile[64][65];
  int tr = threadIdx.x >> 2;
  int g  = threadIdx.x & 3;
  int c  = c0 + tr;
  float mu = st[(b*128+c)*2];
  float rs = st[(b*128+c)*2+1];
  const u16* src = h2b + (size_t)(b*128+c)*HW + pbase + g*16;
  #pragma unroll
  for (int i=0;i<2;i++){
    short8 v8 = *(const short8*)(src + i*8);
    #pragma unroll
    for (int j=0;j<8;j++){
      float v = (bu2f((u16)v8[j]) - mu)*rs;
      tile[tr][g*16 + i*8 + j] = v;
    }
  }
  __syncthreads();
  int pr = tr;
  u16* dt = dscT + ((size_t)b*HW + pbase + pr)*NC + c0 + g*16;
  #pragma unroll
  for (int i=0;i<4;i++){
    float v0 = tile[g*16+i*4+0][pr], v1 = tile[g*16+i*4+1][pr];
    float v2 = tile[g*16+i*4+2][pr], v3 = tile[g*16+i*4+3][pr];
    ushort4 hi = make_ushort4(f2b(v0), f2b(v1), f2b(v2), f2b(v3));
    *(ushort4*)(dt + i*4) = hi;
  }
}

// ---------------- K5: offset conv v3 — full tap per phase (deform's template) ---------
// 9 phases (was 36 steps): per phase, all 256 threads gather the tap's full 128-ch row
// (2x16B per thread), 4 MFMA consume K=128, dbuf + 2-deep pipeline, 18 barriers (was 72).
__global__ __launch_bounds__(256) void off_mfma(const u16* __restrict__ dscT,
    const u16* __restrict__ wobp, const float* __restrict__ off_b,
    float4* __restrict__ wg, ushort4* __restrict__ ad){
  __shared__ short As[2][32*136];            // [buf][32px][128K] pad 136
  __shared__ float Po[18*32];
  int blk = blockIdx.x;                      // 1152 = 8 * 144
  int tile = (blk&7)*144 + (blk>>3);
  int row0 = tile*32;
  int b = rfl(row0/HW); int pbase = rfl(row0 - b*HW);
  int t = threadIdx.x;
  int apx = t>>3, seg8 = t&7;                // 32 px x 8 segs (8ch x 2 halves each)
  int w = rfl(t>>6); int l = t&63; int q = l>>4; int ln = l&15;
  int mt = w&1, ntl = w>>1;
  int P = pbase + apx;
  int py = P/96, px_ = P - 96*py;
  const u16* gsrc = dscT + (size_t)b*HW*NC;
  const u16* wbase = wobp + ntl*18432 + l*8;
  uint4 rgA0, rgA1, rgB0, rgB1;
  short8 bregE[4], bregO[4];
  const uint4 Z = (uint4){0,0,0,0};
  auto issueG = [&](int k, uint4& r0, uint4& r1){
    int y2 = py + k/3 - 1, x2 = px_ + k%3 - 1;
    bool valid = ((unsigned)y2 < 96u) && ((unsigned)x2 < 96u);
    int off = (y2*96 + x2)*NC + seg8*8;
    r0 = valid ? *(const uint4*)(gsrc + off) : Z;
    r1 = valid ? *(const uint4*)(gsrc + off + 64) : Z;
  };
  auto issueB = [&](int k, short8* dst){
    #pragma unroll
    for (int cs=0; cs<4; cs++) dst[cs] = *(const short8*)(wbase + (k*4+cs)*512);
  };
  auto commit = [&](int buf, uint4& r0, uint4& r1){
    *(short8*)&As[buf][apx*136 + seg8*8] = *(short8*)&r0;
    *(short8*)&As[buf][apx*136 + 64 + seg8*8] = *(short8*)&r1;
  };
  v4f acc = (v4f){0.f,0.f,0.f,0.f};
  auto step = [&](int buf, const short8* bb){
    #pragma unroll
    for (int cs=0; cs<4; cs++){
      short8 af = *(const short8*)&As[buf][(mt*16+ln)*136 + cs*32 + q*8];
      acc = __builtin_amdgcn_mfma_f32_16x16x32_bf16(af, bb[cs], acc, 0,0,0);
    }
  };
  issueG(0, rgA0, rgA1); issueB(0, bregE);
  issueG(1, rgB0, rgB1); issueB(1, bregO);
  commit(0, rgA0, rgA1);
  __syncthreads();
  #pragma unroll 1
  for (int k=0;k<9;k+=2){
    bool m1 = (k+1<9), m2 = (k+2<9), m3 = (k+3<9);
    if (m2) issueG(k+2, rgA0, rgA1);
    if (m1) commit(1, rgB0, rgB1);           // stage k+1 -> buf1
    step(0, bregE);                          // MFMA(k)
    if (m2) issueB(k+2, bregE);
    __syncthreads();
    if (m1){
      if (m3) issueG(k+3, rgB0, rgB1);
      if (m2) commit(0, rgA0, rgA1);         // stage k+2 -> buf0
      step(1, bregO);                        // MFMA(k+1)
      if (m3) issueB(k+3, bregO);
      __syncthreads();
    }
  }
  int o = ntl*16 + ln;
  if (o < 18){
    float ob = off_b[o];
    #pragma unroll
    for (int r=0;r<4;r++) Po[o*32 + mt*16 + q*4 + r] = acc[r] + ob;
  }
  __syncthreads();
  #pragma unroll
  for (int i=0;i<2;i++){
    int idx = i*256 + t;
    if (idx < 288){
      int pxl = idx & 31, k = idx >> 5;
      int Pp = pbase + pxl;
      float dy = Po[(2*k)*32 + pxl], dx = Po[(2*k+1)*32 + pxl];
      float ys = (float)(Pp/96 + k/3 - 1) + dy;
      float xs = (float)(Pp%96 + k%3 - 1) + dx;
      float fy0 = floorf(ys), fx0 = floorf(xs);
      float wy = ys - fy0, wx = xs - fx0;
      int y0 = (int)fy0, x0 = (int)fx0;
      int y1 = y0+1, x1 = x0+1;
      float vy0 = (y0>=0 && y0<=95) ? 1.f : 0.f;
      float vy1 = (y1>=0 && y1<=95) ? 1.f : 0.f;
      float vx0 = (x0>=0 && x0<=95) ? 1.f : 0.f;
      float vx1 = (x1>=0 && x1<=95) ? 1.f : 0.f;
      int y0c=min(max(y0,0),95), y1c=min(max(y1,0),95);
      int x0c=min(max(x0,0),95), x1c=min(max(x1,0),95);
      float4 w4;
      w4.x = (1.f-wy)*(1.f-wx)*vy0*vx0;
      w4.y = (1.f-wy)*wx*vy0*vx1;
      w4.z = wy*(1.f-wx)*vy1*vx0;
      w4.w = wy*wx*vy1*vx1;
      int gi = (b*9 + k)*HW + pbase + pxl;
      wg[gi] = w4;
      ad[gi] = make_ushort4((u16)(y0c*WD+x0c), (u16)(y0c*WD+x1c),
                            (u16)(y1c*WD+x0c), (u16)(y1c*WD+x1c));
    }
  }
}

// ---------------- K6: deform conv + fused epilogue (round 16, unchanged) --------------
__global__ __launch_bounds__(256) void deform_mfma(const u16* __restrict__ dscT,
    const u16* __restrict__ wdcb, const float* __restrict__ dc_b,
    const float4* __restrict__ wg, const ushort4* __restrict__ ad,
    const float* __restrict__ ln_g, const float* __restrict__ ln_b,
    float* __restrict__ out){
  __shared__ short As[2][32*68];
  __shared__ float4 WgL[288];
  __shared__ ushort4 AdL[288];
  __shared__ float RS[2][4][4][4];
  __shared__ u16 DT[32*128];                 // dscT tile for the gate multiply
  int blk = blockIdx.x;                      // 1152 = 8 * 144
  int tile = (blk&7)*144 + (blk>>3);
  int row0 = tile*32;
  int b = rfl(row0/HW); int pbase = rfl(row0 - b*HW);
  int t = threadIdx.x;
  int apx = t>>3, cs8 = t&7;
  int w = rfl(t>>6); int l = t&63; int q = l>>4; int ln = l&15;
  int mt = w&1, nb = (w>>1)*4, rrole = rfl(w>>1);
  const u16* db0 = dscT + (size_t)b*HW*NC + cs8*8;
  const u16* wbase = wdcb + (size_t)rrole*(18*4096) + l*8;
  #pragma unroll
  for (int i=0;i<2;i++){
    int idx = i*256 + t;
    if (idx < 288){ int k = idx>>5, pxl = idx&31; int gi = (b*9+k)*HW + pbase + pxl;
      WgL[idx] = wg[gi]; AdL[idx] = ad[gi]; }
  }
  __syncthreads();
  uint4 gA0,gA1,gA2,gA3, gB0,gB1,gB2,gB3;
  float4 wvA, wvB;
  short8 bregE[8], bregO[8];
  auto issueG = [&](int s, float4& wv, uint4& r0, uint4& r1, uint4& r2, uint4& r3){
    int k = s>>1, cb = (s&1)<<6;
    ushort4 av = AdL[k*32+apx]; wv = WgL[k*32+apx];
    const u16* db = db0 + cb;
    r0 = *(const uint4*)(db + (int)av.x*NC);
    r1 = *(const uint4*)(db + (int)av.y*NC);
    r2 = *(const uint4*)(db + (int)av.z*NC);
    r3 = *(const uint4*)(db + (int)av.w*NC);
  };
  auto issueB = [&](int s, short8* dst){
    const u16* p = wbase + s*4096;
    #pragma unroll
    for (int f=0;f<8;f++) dst[f] = *(const short8*)(p + f*512);
  };
  auto commitA = [&](int buf, float4 wv, uint4& r0, uint4& r1, uint4& r2, uint4& r3){
    const u16* pa=(const u16*)&r0; const u16* pb=(const u16*)&r1;
    const u16* pc=(const u16*)&r2; const u16* pd=(const u16*)&r3;
    short8 sv;
    #pragma unroll
    for (int j=0;j<8;j++){
      float f = wv.x*bu2f(pa[j]) + wv.y*bu2f(pb[j]) + wv.z*bu2f(pc[j]) + wv.w*bu2f(pd[j]);
      sv[j] = (short)f2b(f);
    }
    *(short8*)&As[buf][apx*68 + cs8*8] = sv;
  };
  v4f acc[4];
  #pragma unroll
  for (int nt=0;nt<4;nt++) acc[nt] = (v4f){0.f,0.f,0.f,0.f};
  auto step = [&](int buf, const short8* bb){
    #pragma unroll
    for (int ks=0;ks<2;ks++){
      short8 af = *(const short8*)&As[buf][(mt*16+ln)*68 + ks*32 + q*8];
      #pragma unroll
      for (int nt=0;nt<4;nt++)
        acc[nt] = __builtin_amdgcn_mfma_f32_16x16x32_bf16(af, bb[nt*2+ks], acc[nt], 0,0,0);
    }
  };
  issueG(0, wvA, gA0,gA1,gA2,gA3); issueB(0, bregE);
  issueG(1, wvB, gB0,gB1,gB2,gB3); issueB(1, bregO);
  commitA(0, wvA, gA0,gA1,gA2,gA3);
  __syncthreads();
  #pragma unroll 1
  for (int s=0;s<18;s+=2){
    if (s+2<18) issueG(s+2, wvA, gA0,gA1,gA2,gA3);
    commitA(1, wvB, gB0,gB1,gB2,gB3);
    step(0, bregE);
    if (s+2<18) issueB(s+2, bregE);
    __syncthreads();
    if (s+3<18) issueG(s+3, wvB, gB0,gB1,gB2,gB3);
    if (s+2<18) commitA(0, wvA, gA0,gA1,gA2,gA3);
    step(1, bregO);
    if (s+3<18) issueB(s+3, bregO);
    __syncthreads();
  }
  // ---- fused epilogue ----
  int o_[4]; float bias_[4], g_[4], bb_[4];
  #pragma unroll
  for (int nt=0;nt<4;nt++){
    int o = (nb+nt)*16 + ln;
    o_[nt] = o; bias_[nt] = dc_b[o]; g_[nt] = ln_g[o]; bb_[nt] = ln_b[o];
  }
  float s_[4] = {0.f,0.f,0.f,0.f}, ss_[4] = {0.f,0.f,0.f,0.f};
  #pragma unroll
  for (int r=0;r<4;r++){
    #pragma unroll
    for (int nt=0;nt<4;nt++){
      float v = acc[nt][r] + bias_[nt];
      s_[r] += v; ss_[r] = fmaf(v, v, ss_[r]);
    }
  }
  #pragma unroll
  for (int off=1; off<16; off<<=1){
    #pragma unroll
    for (int r=0;r<4;r++){
      s_[r]  += __shfl_xor(s_[r],  off);
      ss_[r] += __shfl_xor(ss_[r], off);
    }
  }
  if (ln==0){
    #pragma unroll
    for (int r=0;r<4;r++){ RS[0][w][q][r] = s_[r]; RS[1][w][q][r] = ss_[r]; }
  }
  // stage the block's dscT tile (contiguous 32*128 u16 = 8KB) for the gate multiply
  {
    const u16* dsrc = dscT + ((size_t)b*HW + pbase)*NC;
    #pragma unroll
    for (int i=0;i<2;i++){
      int idx = i*256 + t;
      *(short8*)&DT[idx*8] = *(const short8*)(dsrc + idx*8);
    }
  }
  __syncthreads();
  float m_[4], rs_[4];
  #pragma unroll
  for (int r=0;r<4;r++){
    float S  = RS[0][w][q][r] + RS[0][w^2][q][r];
    float SS = RS[1][w][q][r] + RS[1][w^2][q][r];
    float m = S*(1.f/128.f);
    float var = SS*(1.f/128.f) - m*m;
    m_[r] = m; rs_[r] = rsqrtf(var + 1e-5f);
  }
  int pxb = pbase + mt*16 + q*4;
  int lpx = mt*16 + q*4;
  #pragma unroll
  for (int nt=0;nt<4;nt++){
    size_t base = (size_t)(b*NC + o_[nt])*HW + pxb;
    float4 ov;
    #pragma unroll
    for (int r=0;r<4;r++){
      float v = acc[nt][r] + bias_[nt];
      float lnv = (v - m_[r])*rs_[r]*g_[nt] + bb_[nt];
      float attn = 1.f/(1.f+__expf(-lnv));
      float dv = bu2f(DT[(lpx+r)*128 + o_[nt]]);
      ((float*)&ov)[r] = dv * attn;
    }
    *(float4*)(out + base) = ov;
  }
}

extern "C" void kernel_launch(void* const* d_in, const int* in_sizes, int n_in,
                              void* d_out, int out_size, void* d_ws, size_t ws_size,
                              hipStream_t stream){
  const float* x    = (const float*)d_in[0];
  const float* dw_w = (const float*)d_in[1];
  const float* dw_b = (const float*)d_in[2];
  const float* pw_w = (const float*)d_in[3];
  const float* pw_b = (const float*)d_in[4];
  const float* off_w= (const float*)d_in[5];
  const float* off_b= (const float*)d_in[6];
  const float* dc_w = (const float*)d_in[7];
  const float* dc_b = (const float*)d_in[8];
  const float* ln_g = (const float*)d_in[9];
  const float* ln_b = (const float*)d_in[10];
  float* out = (float*)d_out;

  float* W    = (float*)d_ws;
  u16*     h1b  = (u16*)W;                    // h1 bf16
  u16*     h2b  = (u16*)(W + 4718592);        // h2 bf16
  u16*     dscT = (u16*)(W + 9437184);        // NHWC bf16
  float4*  wg   = (float4*)(W + 14155776);    // 331776 float4
  ushort4* ad   = (ushort4*)(W + 15482880);   // 331776 ushort4
  float*   st   = W + 16146432;               // 1024 floats (mu, rs per b,c)
  u16*     wpwb = (u16*)(W + 16147456);       // 16384 u16
  u16*     wob  = (u16*)(W + 16155648);       // 36864 u16 (fragment-permuted)
  u16*     wdcb = (u16*)(W + 16174080);       // 147456 u16 (fragment-permuted)

  prep_weights<<<576, 256, 0, stream>>>(pw_w, off_w, dc_w, wpwb, wob, wdcb);
  dw_conv     <<<4608, 256, 0, stream>>>(x, dw_w, dw_b, h1b);
  pw_mfma     <<<576, 256, 0, stream>>>(h1b, wpwb, pw_b, h2b);
  inorm_stats <<<512, 256, 0, stream>>>(h2b, st);
  make_dsc    <<<1152, 256, 0, stream>>>(h2b, st, dscT);
  off_mfma    <<<1152, 256, 0, stream>>>(dscT, wob, off_b, wg, ad);
  deform_mfma <<<1152, 256, 0, stream>>>(dscT, wdcb, dc_b, wg, ad, ln_g, ln_b, out);
}